// Round 1
// baseline (503.265 us; speedup 1.0000x reference)
//
#include <hip/hip_runtime.h>

// ---------------------------------------------------------------------------
// Transformer block for MI355X (gfx950).
//   x:[2,2048,1024] fp32.  All GEMMs in bf16 MFMA (16x16x32), fp32 accum.
//   Residual/LN paths kept fp32.  Weights pre-transposed to [N][K] bf16 so
//   both MFMA operands are k-contiguous (global_load_lds staging, m97-style).
// Workspace layout (88 MB used):
//   tw_qkv | tw_proj | tfc1 | tfc2 | xn | qkv(+vt) | attn | x1 ; h1 aliases qkv+vt
// ---------------------------------------------------------------------------

typedef short  bf16x8 __attribute__((ext_vector_type(8)));
typedef short  bf16x4 __attribute__((ext_vector_type(4)));
typedef float  fx4    __attribute__((ext_vector_type(4)));

#define DEV static __device__ __forceinline__

DEV short f2bf(float f) {                 // round-to-nearest-even fp32 -> bf16
    unsigned u = __builtin_bit_cast(unsigned, f);
    u += 0x7fffu + ((u >> 16) & 1u);
    return (short)(u >> 16);
}

// address-space casts for global_load_lds (C-style cast performs addrspacecast)
#define AS1(p) ((__attribute__((address_space(1))) void*)(p))
#define AS3(p) ((__attribute__((address_space(3))) void*)(p))

// ---------------------------------------------------------------------------
// LayerNorm: fp32 [4096][1024] -> bf16 [4096][1024].  One block (256t) / row.
// ---------------------------------------------------------------------------
__global__ __launch_bounds__(256) void ln_kernel(const float* __restrict__ x,
                                                 const float* __restrict__ w,
                                                 const float* __restrict__ b,
                                                 short* __restrict__ out)
{
    int row = blockIdx.x;
    int tid = threadIdx.x;
    const float4 v = *(const float4*)(x + (size_t)row * 1024 + tid * 4);
    float s = v.x + v.y + v.z + v.w;
    float q = v.x * v.x + v.y * v.y + v.z * v.z + v.w * v.w;
#pragma unroll
    for (int off = 32; off > 0; off >>= 1) {
        s += __shfl_down(s, off);
        q += __shfl_down(q, off);
    }
    __shared__ float ls[4], lq[4];
    if ((tid & 63) == 0) { ls[tid >> 6] = s; lq[tid >> 6] = q; }
    __syncthreads();
    float S  = ls[0] + ls[1] + ls[2] + ls[3];
    float Q  = lq[0] + lq[1] + lq[2] + lq[3];
    float mu  = S * (1.0f / 1024.0f);
    float var = Q * (1.0f / 1024.0f) - mu * mu;
    float inv = rsqrtf(var + 1e-5f);
    float4 wv = *(const float4*)(w + tid * 4);
    float4 bv = *(const float4*)(b + tid * 4);
    bf16x4 o;
    o[0] = f2bf((v.x - mu) * inv * wv.x + bv.x);
    o[1] = f2bf((v.y - mu) * inv * wv.y + bv.y);
    o[2] = f2bf((v.z - mu) * inv * wv.z + bv.z);
    o[3] = f2bf((v.w - mu) * inv * wv.w + bv.w);
    *(bf16x4*)(out + (size_t)row * 1024 + tid * 4) = o;
}

// ---------------------------------------------------------------------------
// Weight transpose+cast: fp32 [R][C] -> bf16 [C][R].  32x32 tiles, block 32x8.
// ---------------------------------------------------------------------------
__global__ void transpose_f32_bf16(const float* __restrict__ in,
                                   short* __restrict__ out, int R, int C)
{
    __shared__ float tile[32][33];
    int c0 = blockIdx.x * 32, r0 = blockIdx.y * 32;
    int tx = threadIdx.x, ty = threadIdx.y;
#pragma unroll
    for (int dy = 0; dy < 32; dy += 8)
        tile[ty + dy][tx] = in[(size_t)(r0 + ty + dy) * C + c0 + tx];
    __syncthreads();
#pragma unroll
    for (int dy = 0; dy < 32; dy += 8)
        out[(size_t)(c0 + ty + dy) * R + r0 + tx] = f2bf(tile[tx][ty + dy]);
}

// ---------------------------------------------------------------------------
// Extract V^T per (b,h): qkv bf16 [4096][3072] cols[2048+h*64 .. +64)
//   -> vt [b][h][64][2048] (d-major, t contiguous) for PV's B-operand.
// ---------------------------------------------------------------------------
__global__ void vt_extract(const short* __restrict__ qkv, short* __restrict__ vt)
{
    __shared__ short tile[32][33];
    int t0 = blockIdx.x * 32, d0 = blockIdx.y * 32;
    int bh = blockIdx.z;                       // b*16 + h
    int tx = threadIdx.x, ty = threadIdx.y;
    size_t inbase  = (size_t)(bh >> 4) * 2048 * 3072 + 2048 + (bh & 15) * 64;
    size_t outbase = (size_t)bh * 64 * 2048;
#pragma unroll
    for (int dy = 0; dy < 32; dy += 8)
        tile[ty + dy][tx] = qkv[inbase + (size_t)(t0 + ty + dy) * 3072 + d0 + tx];
    __syncthreads();
#pragma unroll
    for (int dy = 0; dy < 32; dy += 8)
        vt[outbase + (size_t)(d0 + ty + dy) * 2048 + t0 + tx] = tile[tx][ty + dy];
}

// ---------------------------------------------------------------------------
// GEMM  C[M][N] = epi( A[M][K](bf16) * Bt[N][K](bf16)^T )
// 128x128 tile / 256 threads, BK=32, global_load_lds(16B) staging (m97 shape).
// Epilogue fusions: +bias[N], exact GELU, +resid(fp32)[M][N], out fp32|bf16.
// ---------------------------------------------------------------------------
template <bool BIAS, bool GELU, bool RESID, bool OUT_BF16>
__global__ __launch_bounds__(256) void gemm_bt(const short* __restrict__ A,
                                               const short* __restrict__ Bt,
                                               void* __restrict__ Cout,
                                               const float* __restrict__ bias,
                                               const float* __restrict__ resid,
                                               int M, int N, int K)
{
    __shared__ short As[128 * 32];
    __shared__ short Bs[128 * 32];
    int tid  = threadIdx.x;
    int lane = tid & 63, wv = tid >> 6;
    int quad = lane >> 4, l15 = lane & 15;
    int m0 = blockIdx.y * 128, n0 = blockIdx.x * 128;
    int wr = (wv >> 1) * 64, wc = (wv & 1) * 64;   // wave's 64x64 quadrant
    fx4 acc[4][4] = {};
    int srow = lane >> 2;                          // staging: 16 rows / chunk
    int scol = (lane & 3) * 8;
    const short* Ab = A  + (size_t)m0 * K;
    const short* Bb = Bt + (size_t)n0 * K;

    for (int k0 = 0; k0 < K; k0 += 32) {
#pragma unroll
        for (int j = 0; j < 2; ++j) {              // 2 x 1KB per wave per array
            int c   = wv + j * 4;                  // chunk 0..7
            int row = c * 16 + srow;
            __builtin_amdgcn_global_load_lds(AS1(Ab + (size_t)row * K + k0 + scol),
                                             AS3(&As[c * 512]), 16, 0, 0);
            __builtin_amdgcn_global_load_lds(AS1(Bb + (size_t)row * K + k0 + scol),
                                             AS3(&Bs[c * 512]), 16, 0, 0);
        }
        __syncthreads();
        bf16x8 af[4], bf[4];
#pragma unroll
        for (int i = 0; i < 4; ++i)
            af[i] = *(const bf16x8*)&As[(wr + i * 16 + l15) * 32 + quad * 8];
#pragma unroll
        for (int j = 0; j < 4; ++j)
            bf[j] = *(const bf16x8*)&Bs[(wc + j * 16 + l15) * 32 + quad * 8];
#pragma unroll
        for (int i = 0; i < 4; ++i)
#pragma unroll
            for (int j = 0; j < 4; ++j)
                acc[i][j] = __builtin_amdgcn_mfma_f32_16x16x32_bf16(af[i], bf[j], acc[i][j], 0, 0, 0);
        __syncthreads();
    }

#pragma unroll
    for (int i = 0; i < 4; ++i) {
#pragma unroll
        for (int j = 0; j < 4; ++j) {
#pragma unroll
            for (int r = 0; r < 4; ++r) {
                int row = m0 + wr + i * 16 + quad * 4 + r;
                int col = n0 + wc + j * 16 + l15;
                float v = acc[i][j][r];
                if constexpr (BIAS)  v += bias[col];
                if constexpr (GELU)  v = 0.5f * v * (1.0f + erff(v * 0.70710678118654752f));
                if constexpr (RESID) v += resid[(size_t)row * N + col];
                if constexpr (OUT_BF16) ((short*)Cout)[(size_t)row * N + col] = f2bf(v);
                else                    ((float*)Cout)[(size_t)row * N + col] = v;
            }
        }
    }
}

// ---------------------------------------------------------------------------
// Flash attention (causal).  Block = 128 Q rows (4 waves x 32), K/V tiles = 64.
// Q frags register-resident; K tile and V^T tile staged via global_load_lds;
// P round-trips through per-wave-private LDS for the C-layout -> A-layout fix.
// ---------------------------------------------------------------------------
__global__ __launch_bounds__(256) void attn_kernel(const short* __restrict__ qkv,
                                                   const short* __restrict__ vt,
                                                   short* __restrict__ out)
{
    __shared__ short Ks[64 * 64];
    __shared__ short Vs[64 * 64];
    __shared__ short Ps[4 * 32 * 64];
    const float CS = 0.125f * 1.44269504088896f;  // 1/sqrt(64) * log2(e)
    int tid  = threadIdx.x, lane = tid & 63, wv = tid >> 6;
    int quad = lane >> 4, l15 = lane & 15;
    int b = blockIdx.z, h = blockIdx.y, q0 = blockIdx.x * 128;

    bf16x8 qf[2][2];
#pragma unroll
    for (int mt = 0; mt < 2; ++mt)
#pragma unroll
        for (int ks = 0; ks < 2; ++ks)
            qf[mt][ks] = *(const bf16x8*)&qkv[(size_t)(b * 2048 + q0 + wv * 32 + mt * 16 + l15) * 3072
                                              + h * 64 + ks * 32 + quad * 8];
    float mi[2][4], li[2][4];
    fx4 oacc[2][4] = {};
#pragma unroll
    for (int mt = 0; mt < 2; ++mt)
#pragma unroll
        for (int r = 0; r < 4; ++r) { mi[mt][r] = -1e30f; li[mt][r] = 0.0f; }

    const size_t kbase = (size_t)b * 2048 * 3072 + 1024 + h * 64;
    const size_t vbase = (size_t)(b * 16 + h) * 64 * 2048;
    int srow = lane >> 3;            // staging: 8 rows / chunk (128B rows)
    int scol = (lane & 7) * 8;
    int ktmax = (q0 >> 6) + 2;

    for (int kt = 0; kt < ktmax; ++kt) {
        int t0 = kt * 64;
#pragma unroll
        for (int j = 0; j < 2; ++j) {
            int c   = wv + j * 4;
            int row = c * 8 + srow;
            __builtin_amdgcn_global_load_lds(AS1(qkv + kbase + (size_t)(t0 + row) * 3072 + scol),
                                             AS3(&Ks[c * 512]), 16, 0, 0);
            __builtin_amdgcn_global_load_lds(AS1(vt + vbase + (size_t)row * 2048 + t0 + scol),
                                             AS3(&Vs[c * 512]), 16, 0, 0);
        }
        __syncthreads();

        fx4 s[2][4];
#pragma unroll
        for (int mt = 0; mt < 2; ++mt) {
#pragma unroll
            for (int nt = 0; nt < 4; ++nt) {
                bf16x8 kf0 = *(const bf16x8*)&Ks[(nt * 16 + l15) * 64 + quad * 8];
                bf16x8 kf1 = *(const bf16x8*)&Ks[(nt * 16 + l15) * 64 + 32 + quad * 8];
                fx4 z = {0.f, 0.f, 0.f, 0.f};
                z = __builtin_amdgcn_mfma_f32_16x16x32_bf16(qf[mt][0], kf0, z, 0, 0, 0);
                z = __builtin_amdgcn_mfma_f32_16x16x32_bf16(qf[mt][1], kf1, z, 0, 0, 0);
                s[mt][nt] = z;
            }
        }
        if (kt >= (q0 >> 6)) {                     // only the last two tiles touch the diagonal
#pragma unroll
            for (int mt = 0; mt < 2; ++mt)
#pragma unroll
                for (int nt = 0; nt < 4; ++nt)
#pragma unroll
                    for (int r = 0; r < 4; ++r) {
                        int row = q0 + wv * 32 + mt * 16 + quad * 4 + r;
                        int col = t0 + nt * 16 + l15;
                        if (col > row) s[mt][nt][r] = -1e30f;
                    }
        }
#pragma unroll
        for (int mt = 0; mt < 2; ++mt) {
            float mnew[4], alpha[4], rsum[4];
#pragma unroll
            for (int r = 0; r < 4; ++r) {
                float v = fmaxf(fmaxf(s[mt][0][r], s[mt][1][r]), fmaxf(s[mt][2][r], s[mt][3][r]));
#pragma unroll
                for (int d = 1; d < 16; d <<= 1) v = fmaxf(v, __shfl_xor(v, d));
                mnew[r]  = fmaxf(mi[mt][r], v);
                alpha[r] = exp2f((mi[mt][r] - mnew[r]) * CS);
                mi[mt][r] = mnew[r];
                rsum[r] = 0.0f;
            }
#pragma unroll
            for (int nt = 0; nt < 4; ++nt)
#pragma unroll
                for (int r = 0; r < 4; ++r) {
                    float p = exp2f((s[mt][nt][r] - mnew[r]) * CS);
                    rsum[r] += p;
                    Ps[wv * 2048 + (mt * 16 + quad * 4 + r) * 64 + nt * 16 + l15] = f2bf(p);
                }
#pragma unroll
            for (int r = 0; r < 4; ++r) {
                float v = rsum[r];
#pragma unroll
                for (int d = 1; d < 16; d <<= 1) v += __shfl_xor(v, d);
                li[mt][r] = li[mt][r] * alpha[r] + v;
#pragma unroll
                for (int dt = 0; dt < 4; ++dt) oacc[mt][dt][r] *= alpha[r];
            }
        }
        __syncthreads();   // order P stores before fragment reads
#pragma unroll
        for (int mt = 0; mt < 2; ++mt) {
            bf16x8 pf0 = *(const bf16x8*)&Ps[wv * 2048 + (mt * 16 + l15) * 64 + quad * 8];
            bf16x8 pf1 = *(const bf16x8*)&Ps[wv * 2048 + (mt * 16 + l15) * 64 + 32 + quad * 8];
#pragma unroll
            for (int dt = 0; dt < 4; ++dt) {
                bf16x8 vf0 = *(const bf16x8*)&Vs[(dt * 16 + l15) * 64 + quad * 8];
                bf16x8 vf1 = *(const bf16x8*)&Vs[(dt * 16 + l15) * 64 + 32 + quad * 8];
                oacc[mt][dt] = __builtin_amdgcn_mfma_f32_16x16x32_bf16(pf0, vf0, oacc[mt][dt], 0, 0, 0);
                oacc[mt][dt] = __builtin_amdgcn_mfma_f32_16x16x32_bf16(pf1, vf1, oacc[mt][dt], 0, 0, 0);
            }
        }
        __syncthreads();   // before next-iteration staging clobbers Ks/Vs
    }

#pragma unroll
    for (int mt = 0; mt < 2; ++mt)
#pragma unroll
        for (int dt = 0; dt < 4; ++dt)
#pragma unroll
            for (int r = 0; r < 4; ++r) {
                int row = q0 + wv * 32 + mt * 16 + quad * 4 + r;
                int col = h * 64 + dt * 16 + l15;
                out[((size_t)b * 2048 + row) * 1024 + col] = f2bf(oacc[mt][dt][r] / li[mt][r]);
            }
}

// ---------------------------------------------------------------------------
extern "C" void kernel_launch(void* const* d_in, const int* in_sizes, int n_in,
                              void* d_out, int out_size, void* d_ws, size_t ws_size,
                              hipStream_t stream)
{
    const float* x      = (const float*)d_in[0];
    const float* w_qkv  = (const float*)d_in[1];
    const float* w_proj = (const float*)d_in[2];
    const float* ln1_w  = (const float*)d_in[3];
    const float* ln1_b  = (const float*)d_in[4];
    const float* ln2_w  = (const float*)d_in[5];
    const float* ln2_b  = (const float*)d_in[6];
    const float* fc1_w  = (const float*)d_in[7];
    const float* fc1_b  = (const float*)d_in[8];
    const float* fc2_w  = (const float*)d_in[9];
    const float* fc2_b  = (const float*)d_in[10];
    float* out = (float*)d_out;
    char*  ws  = (char*)d_ws;

    size_t off = 0;
    auto alloc = [&](size_t bytes) { void* p = ws + off; off += (bytes + 255) & ~(size_t)255; return p; };
    short* tw_qkv  = (short*)alloc((size_t)3072 * 1024 * 2);
    short* tw_proj = (short*)alloc((size_t)1024 * 1024 * 2);
    short* tfc1    = (short*)alloc((size_t)4096 * 1024 * 2);
    short* tfc2    = (short*)alloc((size_t)1024 * 4096 * 2);
    short* xn      = (short*)alloc((size_t)4096 * 1024 * 2);
    short* qkvb    = (short*)alloc((size_t)4096 * 3072 * 2);
    short* vtb     = (short*)alloc((size_t)32 * 64 * 2048 * 2);
    short* attnb   = (short*)alloc((size_t)4096 * 1024 * 2);
    float* x1      = (float*)alloc((size_t)4096 * 1024 * 4);
    short* h1      = qkvb;  // alias: qkv(25.2MB)+vt(8.4MB) dead after attention; h1 = 33.55MB

    dim3 tb(32, 8);
    transpose_f32_bf16<<<dim3(3072 / 32, 1024 / 32), tb, 0, stream>>>(w_qkv, tw_qkv, 1024, 3072);
    transpose_f32_bf16<<<dim3(1024 / 32, 1024 / 32), tb, 0, stream>>>(w_proj, tw_proj, 1024, 1024);
    transpose_f32_bf16<<<dim3(4096 / 32, 1024 / 32), tb, 0, stream>>>(fc1_w, tfc1, 1024, 4096);
    transpose_f32_bf16<<<dim3(1024 / 32, 4096 / 32), tb, 0, stream>>>(fc2_w, tfc2, 4096, 1024);

    ln_kernel<<<4096, 256, 0, stream>>>(x, ln1_w, ln1_b, xn);
    gemm_bt<false, false, false, true><<<dim3(3072 / 128, 4096 / 128), 256, 0, stream>>>(
        xn, tw_qkv, qkvb, nullptr, nullptr, 4096, 3072, 1024);
    vt_extract<<<dim3(2048 / 32, 64 / 32, 32), tb, 0, stream>>>(qkvb, vtb);
    attn_kernel<<<dim3(16, 16, 2), 256, 0, stream>>>(qkvb, vtb, attnb);
    gemm_bt<false, false, true, false><<<dim3(1024 / 128, 4096 / 128), 256, 0, stream>>>(
        attnb, tw_proj, x1, nullptr, x, 4096, 1024, 1024);
    ln_kernel<<<4096, 256, 0, stream>>>(x1, ln2_w, ln2_b, xn);
    gemm_bt<true, true, false, true><<<dim3(4096 / 128, 4096 / 128), 256, 0, stream>>>(
        xn, tfc1, h1, fc1_b, nullptr, 4096, 4096, 1024);
    gemm_bt<true, false, true, false><<<dim3(1024 / 128, 4096 / 128), 256, 0, stream>>>(
        h1, tfc2, out, fc2_b, x1, 4096, 1024, 4096);
}

// Round 2
// 447.935 us; speedup vs baseline: 1.1235x; 1.1235x over previous
//
#include <hip/hip_runtime.h>

// ---------------------------------------------------------------------------
// Transformer block for MI355X (gfx950).  R2: attention rewritten —
//   64-row Q tiles (1024 blocks, longest-first), DPP rotate-reduce softmax
//   (VALU pipe, no ds_swizzle), XOR-swizzled LDS (conflict-free b128 reads),
//   2 barriers/kt.  GEMM gains a BN=64 tile variant for N=1024 outputs
//   (proj, fc2) to get >=2 blocks/CU.
// ---------------------------------------------------------------------------

typedef short  bf16x8 __attribute__((ext_vector_type(8)));
typedef short  bf16x4 __attribute__((ext_vector_type(4)));
typedef float  fx4    __attribute__((ext_vector_type(4)));

#define DEV static __device__ __forceinline__

DEV short f2bf(float f) {                 // round-to-nearest-even fp32 -> bf16
    unsigned u = __builtin_bit_cast(unsigned, f);
    u += 0x7fffu + ((u >> 16) & 1u);
    return (short)(u >> 16);
}

// 16-lane (DPP "row") rotate-reduce on the VALU pipe. row_ror:N = 0x120|N.
template <int CTRL> DEV float dppmax(float v) {
    int x = __builtin_amdgcn_update_dpp(0, __builtin_bit_cast(int, v), CTRL, 0xF, 0xF, true);
    return fmaxf(v, __builtin_bit_cast(float, x));
}
template <int CTRL> DEV float dppadd(float v) {
    int x = __builtin_amdgcn_update_dpp(0, __builtin_bit_cast(int, v), CTRL, 0xF, 0xF, true);
    return v + __builtin_bit_cast(float, x);
}
DEV float rowmax16(float v) {
    v = dppmax<0x121>(v); v = dppmax<0x122>(v); v = dppmax<0x124>(v); v = dppmax<0x128>(v);
    return v;
}
DEV float rowsum16(float v) {
    v = dppadd<0x121>(v); v = dppadd<0x122>(v); v = dppadd<0x124>(v); v = dppadd<0x128>(v);
    return v;
}

// address-space casts for global_load_lds
#define AS1(p) ((__attribute__((address_space(1))) void*)(p))
#define AS3(p) ((__attribute__((address_space(3))) void*)(p))

// ---------------------------------------------------------------------------
// LayerNorm: fp32 [4096][1024] -> bf16 [4096][1024].  One block (256t) / row.
// ---------------------------------------------------------------------------
__global__ __launch_bounds__(256) void ln_kernel(const float* __restrict__ x,
                                                 const float* __restrict__ w,
                                                 const float* __restrict__ b,
                                                 short* __restrict__ out)
{
    int row = blockIdx.x;
    int tid = threadIdx.x;
    const float4 v = *(const float4*)(x + (size_t)row * 1024 + tid * 4);
    float s = v.x + v.y + v.z + v.w;
    float q = v.x * v.x + v.y * v.y + v.z * v.z + v.w * v.w;
#pragma unroll
    for (int off = 32; off > 0; off >>= 1) {
        s += __shfl_down(s, off);
        q += __shfl_down(q, off);
    }
    __shared__ float ls[4], lq[4];
    if ((tid & 63) == 0) { ls[tid >> 6] = s; lq[tid >> 6] = q; }
    __syncthreads();
    float S  = ls[0] + ls[1] + ls[2] + ls[3];
    float Q  = lq[0] + lq[1] + lq[2] + lq[3];
    float mu  = S * (1.0f / 1024.0f);
    float var = Q * (1.0f / 1024.0f) - mu * mu;
    float inv = rsqrtf(var + 1e-5f);
    float4 wv = *(const float4*)(w + tid * 4);
    float4 bv = *(const float4*)(b + tid * 4);
    bf16x4 o;
    o[0] = f2bf((v.x - mu) * inv * wv.x + bv.x);
    o[1] = f2bf((v.y - mu) * inv * wv.y + bv.y);
    o[2] = f2bf((v.z - mu) * inv * wv.z + bv.z);
    o[3] = f2bf((v.w - mu) * inv * wv.w + bv.w);
    *(bf16x4*)(out + (size_t)row * 1024 + tid * 4) = o;
}

// ---------------------------------------------------------------------------
// Weight transpose+cast: fp32 [R][C] -> bf16 [C][R].  32x32 tiles, block 32x8.
// ---------------------------------------------------------------------------
__global__ void transpose_f32_bf16(const float* __restrict__ in,
                                   short* __restrict__ out, int R, int C)
{
    __shared__ float tile[32][33];
    int c0 = blockIdx.x * 32, r0 = blockIdx.y * 32;
    int tx = threadIdx.x, ty = threadIdx.y;
#pragma unroll
    for (int dy = 0; dy < 32; dy += 8)
        tile[ty + dy][tx] = in[(size_t)(r0 + ty + dy) * C + c0 + tx];
    __syncthreads();
#pragma unroll
    for (int dy = 0; dy < 32; dy += 8)
        out[(size_t)(c0 + ty + dy) * R + r0 + tx] = f2bf(tile[tx][ty + dy]);
}

// ---------------------------------------------------------------------------
// Extract V^T per (b,h): qkv bf16 [4096][3072] cols[2048+h*64 .. +64)
//   -> vt [b][h][64][2048] (d-major, t contiguous) for PV's B-operand.
// ---------------------------------------------------------------------------
__global__ void vt_extract(const short* __restrict__ qkv, short* __restrict__ vt)
{
    __shared__ short tile[32][33];
    int t0 = blockIdx.x * 32, d0 = blockIdx.y * 32;
    int bh = blockIdx.z;                       // b*16 + h
    int tx = threadIdx.x, ty = threadIdx.y;
    size_t inbase  = (size_t)(bh >> 4) * 2048 * 3072 + 2048 + (bh & 15) * 64;
    size_t outbase = (size_t)bh * 64 * 2048;
#pragma unroll
    for (int dy = 0; dy < 32; dy += 8)
        tile[ty + dy][tx] = qkv[inbase + (size_t)(t0 + ty + dy) * 3072 + d0 + tx];
    __syncthreads();
#pragma unroll
    for (int dy = 0; dy < 32; dy += 8)
        vt[outbase + (size_t)(d0 + ty + dy) * 2048 + t0 + tx] = tile[tx][ty + dy];
}

// ---------------------------------------------------------------------------
// GEMM  C[M][N] = epi( A[M][K](bf16) * Bt[N][K](bf16)^T )
// 128xBN tile / 256 threads, BK=32, global_load_lds(16B) staging (m97 shape).
// BN=128 for wide outputs; BN=64 doubles block count for N=1024 outputs.
// Epilogue fusions: +bias[N], exact GELU, +resid(fp32)[M][N], out fp32|bf16.
// ---------------------------------------------------------------------------
template <int BN, bool BIAS, bool GELU, bool RESID, bool OUT_BF16>
__global__ __launch_bounds__(256) void gemm_bt(const short* __restrict__ A,
                                               const short* __restrict__ Bt,
                                               void* __restrict__ Cout,
                                               const float* __restrict__ bias,
                                               const float* __restrict__ resid,
                                               int M, int N, int K)
{
    constexpr int NJ = BN / 32;                    // 16-col tiles per wave
    __shared__ short As[128 * 32];
    __shared__ short Bs[BN * 32];
    int tid  = threadIdx.x;
    int lane = tid & 63, wv = tid >> 6;
    int quad = lane >> 4, l15 = lane & 15;
    int m0 = blockIdx.y * 128, n0 = blockIdx.x * BN;
    int wr = (wv >> 1) * 64, wc = (wv & 1) * (BN / 2);
    fx4 acc[4][NJ] = {};
    int srow = lane >> 2;                          // staging: 16 rows / chunk
    int scol = (lane & 3) * 8;
    const short* Ab = A  + (size_t)m0 * K;
    const short* Bb = Bt + (size_t)n0 * K;

    for (int k0 = 0; k0 < K; k0 += 32) {
#pragma unroll
        for (int c = wv; c < 8; c += 4) {
            int row = c * 16 + srow;
            __builtin_amdgcn_global_load_lds(AS1(Ab + (size_t)row * K + k0 + scol),
                                             AS3(&As[c * 512]), 16, 0, 0);
        }
#pragma unroll
        for (int c = wv; c < BN / 16; c += 4) {
            int row = c * 16 + srow;
            __builtin_amdgcn_global_load_lds(AS1(Bb + (size_t)row * K + k0 + scol),
                                             AS3(&Bs[c * 512]), 16, 0, 0);
        }
        __syncthreads();
        bf16x8 af[4], bfr[NJ];
#pragma unroll
        for (int i = 0; i < 4; ++i)
            af[i] = *(const bf16x8*)&As[(wr + i * 16 + l15) * 32 + quad * 8];
#pragma unroll
        for (int j = 0; j < NJ; ++j)
            bfr[j] = *(const bf16x8*)&Bs[(wc + j * 16 + l15) * 32 + quad * 8];
#pragma unroll
        for (int i = 0; i < 4; ++i)
#pragma unroll
            for (int j = 0; j < NJ; ++j)
                acc[i][j] = __builtin_amdgcn_mfma_f32_16x16x32_bf16(af[i], bfr[j], acc[i][j], 0, 0, 0);
        __syncthreads();
    }

#pragma unroll
    for (int i = 0; i < 4; ++i) {
#pragma unroll
        for (int j = 0; j < NJ; ++j) {
#pragma unroll
            for (int r = 0; r < 4; ++r) {
                int row = m0 + wr + i * 16 + quad * 4 + r;
                int col = n0 + wc + j * 16 + l15;
                float v = acc[i][j][r];
                if constexpr (BIAS)  v += bias[col];
                if constexpr (GELU)  v = 0.5f * v * (1.0f + erff(v * 0.70710678118654752f));
                if constexpr (RESID) v += resid[(size_t)row * N + col];
                if constexpr (OUT_BF16) ((short*)Cout)[(size_t)row * N + col] = f2bf(v);
                else                    ((float*)Cout)[(size_t)row * N + col] = v;
            }
        }
    }
}

// ---------------------------------------------------------------------------
// Flash attention (causal).  R2 structure:
//   Block = 64 Q rows (4 waves x 16), grid (32,16,2)=1024 blocks, launched
//   longest-first (qt = 31 - blockIdx.x).  K/V tiles = 64, XOR-swizzled LDS:
//   element (row,col) lives at row*64 + ((col>>3)^(row&7))*8 + (col&7) —
//   global_load_lds source addresses absorb the swizzle; b128 fragment reads
//   become phase-balanced (8 lanes per 4-bank group).  Softmax reductions via
//   DPP row_ror (VALU pipe).  Ps is wave-private (DS ops wave-ordered) -> only
//   2 barriers per kt iteration.
// ---------------------------------------------------------------------------
__global__ __launch_bounds__(256) void attn_kernel(const short* __restrict__ qkv,
                                                   const short* __restrict__ vt,
                                                   short* __restrict__ out)
{
    __shared__ short Ks[64 * 64];
    __shared__ short Vs[64 * 64];
    __shared__ short Ps[4 * 16 * 64];
    const float CS = 0.125f * 1.44269504088896f;  // 1/sqrt(64) * log2(e)
    int tid  = threadIdx.x, lane = tid & 63, wv = tid >> 6;
    int quad = lane >> 4, l15 = lane & 15;
    int b = blockIdx.z, h = blockIdx.y;
    int qt = 31 - blockIdx.x;                     // longest blocks first
    int q0 = qt * 64;

    bf16x8 qf[2];
#pragma unroll
    for (int ks = 0; ks < 2; ++ks)
        qf[ks] = *(const bf16x8*)&qkv[(size_t)(b * 2048 + q0 + wv * 16 + l15) * 3072
                                       + h * 64 + ks * 32 + quad * 8];
    float mi[4], li[4];
    fx4 oacc[4] = {};
#pragma unroll
    for (int r = 0; r < 4; ++r) { mi[r] = -1e30f; li[r] = 0.0f; }

    const size_t kbase = (size_t)b * 2048 * 3072 + 1024 + h * 64;
    const size_t vbase = (size_t)(b * 16 + h) * 64 * 2048;
    int srow = lane >> 3;                 // 0..7 : row within 8-row chunk
    int sg   = lane & 7;                  // LDS granule slot
    int scol = (sg ^ srow) * 8;           // global col granule for this slot
    int rg0  = (quad ^ (l15 & 7)) * 8;    // read offset, logical granule=quad
                                          // (row&7 == l15&7 for all frag rows)

    for (int kt = 0; kt <= qt; ++kt) {
        int t0 = kt * 64;
#pragma unroll
        for (int j = 0; j < 2; ++j) {
            int c   = wv + j * 4;
            int row = c * 8 + srow;
            __builtin_amdgcn_global_load_lds(AS1(qkv + kbase + (size_t)(t0 + row) * 3072 + scol),
                                             AS3(&Ks[c * 512]), 16, 0, 0);
            __builtin_amdgcn_global_load_lds(AS1(vt + vbase + (size_t)row * 2048 + t0 + scol),
                                             AS3(&Vs[c * 512]), 16, 0, 0);
        }
        __syncthreads();

        fx4 s[4];
#pragma unroll
        for (int nt = 0; nt < 4; ++nt) {
            bf16x8 kf0 = *(const bf16x8*)&Ks[(nt * 16 + l15) * 64 + rg0];
            bf16x8 kf1 = *(const bf16x8*)&Ks[(nt * 16 + l15) * 64 + (rg0 ^ 32)];
            fx4 z = {0.f, 0.f, 0.f, 0.f};
            z = __builtin_amdgcn_mfma_f32_16x16x32_bf16(qf[0], kf0, z, 0, 0, 0);
            z = __builtin_amdgcn_mfma_f32_16x16x32_bf16(qf[1], kf1, z, 0, 0, 0);
            s[nt] = z;
        }
        if (kt == qt) {                            // diagonal tile: causal mask
#pragma unroll
            for (int nt = 0; nt < 4; ++nt)
#pragma unroll
                for (int r = 0; r < 4; ++r)
                    if (nt * 16 + l15 > wv * 16 + quad * 4 + r) s[nt][r] = -1e30f;
        }

        float mnew[4], alpha[4], rsum[4];
#pragma unroll
        for (int r = 0; r < 4; ++r) {
            float v = fmaxf(fmaxf(s[0][r], s[1][r]), fmaxf(s[2][r], s[3][r]));
            v = rowmax16(v);
            mnew[r]  = fmaxf(mi[r], v);
            alpha[r] = exp2f((mi[r] - mnew[r]) * CS);
            mi[r] = mnew[r];
            rsum[r] = 0.0f;
        }
#pragma unroll
        for (int nt = 0; nt < 4; ++nt)
#pragma unroll
            for (int r = 0; r < 4; ++r) {
                float p = exp2f((s[nt][r] - mnew[r]) * CS);
                rsum[r] += p;
                int rr = quad * 4 + r;
                int col = nt * 16 + l15;
                int g = (col >> 3) ^ (rr & 7);
                Ps[wv * 1024 + rr * 64 + g * 8 + (col & 7)] = f2bf(p);
            }
#pragma unroll
        for (int r = 0; r < 4; ++r) {
            float v = rowsum16(rsum[r]);
            li[r] = li[r] * alpha[r] + v;
#pragma unroll
            for (int dt = 0; dt < 4; ++dt) oacc[dt][r] *= alpha[r];
        }

        // Ps is wave-private; DS ops from a wave are processed in order, so no
        // barrier is needed between the b16 stores above and the b128 reads.
        bf16x8 pf0 = *(const bf16x8*)&Ps[wv * 1024 + l15 * 64 + rg0];
        bf16x8 pf1 = *(const bf16x8*)&Ps[wv * 1024 + l15 * 64 + (rg0 ^ 32)];
#pragma unroll
        for (int dt = 0; dt < 4; ++dt) {
            bf16x8 vf0 = *(const bf16x8*)&Vs[(dt * 16 + l15) * 64 + rg0];
            bf16x8 vf1 = *(const bf16x8*)&Vs[(dt * 16 + l15) * 64 + (rg0 ^ 32)];
            oacc[dt] = __builtin_amdgcn_mfma_f32_16x16x32_bf16(pf0, vf0, oacc[dt], 0, 0, 0);
            oacc[dt] = __builtin_amdgcn_mfma_f32_16x16x32_bf16(pf1, vf1, oacc[dt], 0, 0, 0);
        }
        __syncthreads();   // before next-iteration staging clobbers Ks/Vs
    }

    float inv[4];
#pragma unroll
    for (int r = 0; r < 4; ++r) inv[r] = 1.0f / li[r];
#pragma unroll
    for (int dt = 0; dt < 4; ++dt)
#pragma unroll
        for (int r = 0; r < 4; ++r) {
            int row = q0 + wv * 16 + quad * 4 + r;
            int col = h * 64 + dt * 16 + l15;
            out[((size_t)b * 2048 + row) * 1024 + col] = f2bf(oacc[dt][r] * inv[r]);
        }
}

// ---------------------------------------------------------------------------
extern "C" void kernel_launch(void* const* d_in, const int* in_sizes, int n_in,
                              void* d_out, int out_size, void* d_ws, size_t ws_size,
                              hipStream_t stream)
{
    const float* x      = (const float*)d_in[0];
    const float* w_qkv  = (const float*)d_in[1];
    const float* w_proj = (const float*)d_in[2];
    const float* ln1_w  = (const float*)d_in[3];
    const float* ln1_b  = (const float*)d_in[4];
    const float* ln2_w  = (const float*)d_in[5];
    const float* ln2_b  = (const float*)d_in[6];
    const float* fc1_w  = (const float*)d_in[7];
    const float* fc1_b  = (const float*)d_in[8];
    const float* fc2_w  = (const float*)d_in[9];
    const float* fc2_b  = (const float*)d_in[10];
    float* out = (float*)d_out;
    char*  ws  = (char*)d_ws;

    size_t off = 0;
    auto alloc = [&](size_t bytes) { void* p = ws + off; off += (bytes + 255) & ~(size_t)255; return p; };
    short* tw_qkv  = (short*)alloc((size_t)3072 * 1024 * 2);
    short* tw_proj = (short*)alloc((size_t)1024 * 1024 * 2);
    short* tfc1    = (short*)alloc((size_t)4096 * 1024 * 2);
    short* tfc2    = (short*)alloc((size_t)1024 * 4096 * 2);
    short* xn      = (short*)alloc((size_t)4096 * 1024 * 2);
    short* qkvb    = (short*)alloc((size_t)4096 * 3072 * 2);
    short* vtb     = (short*)alloc((size_t)32 * 64 * 2048 * 2);
    short* attnb   = (short*)alloc((size_t)4096 * 1024 * 2);
    float* x1      = (float*)alloc((size_t)4096 * 1024 * 4);
    short* h1      = qkvb;  // alias: qkv+vt dead after attention; h1 = 33.55MB

    dim3 tb(32, 8);
    transpose_f32_bf16<<<dim3(3072 / 32, 1024 / 32), tb, 0, stream>>>(w_qkv, tw_qkv, 1024, 3072);
    transpose_f32_bf16<<<dim3(1024 / 32, 1024 / 32), tb, 0, stream>>>(w_proj, tw_proj, 1024, 1024);
    transpose_f32_bf16<<<dim3(4096 / 32, 1024 / 32), tb, 0, stream>>>(fc1_w, tfc1, 1024, 4096);
    transpose_f32_bf16<<<dim3(1024 / 32, 4096 / 32), tb, 0, stream>>>(fc2_w, tfc2, 4096, 1024);

    ln_kernel<<<4096, 256, 0, stream>>>(x, ln1_w, ln1_b, xn);
    gemm_bt<128, false, false, false, true><<<dim3(3072 / 128, 4096 / 128), 256, 0, stream>>>(
        xn, tw_qkv, qkvb, nullptr, nullptr, 4096, 3072, 1024);
    vt_extract<<<dim3(2048 / 32, 64 / 32, 32), tb, 0, stream>>>(qkvb, vtb);
    attn_kernel<<<dim3(32, 16, 2), 256, 0, stream>>>(qkvb, vtb, attnb);
    gemm_bt<64, false, false, true, false><<<dim3(1024 / 64, 4096 / 128), 256, 0, stream>>>(
        attnb, tw_proj, x1, nullptr, x, 4096, 1024, 1024);
    ln_kernel<<<4096, 256, 0, stream>>>(x1, ln2_w, ln2_b, xn);
    gemm_bt<128, true, true, false, true><<<dim3(4096 / 128, 4096 / 128), 256, 0, stream>>>(
        xn, tfc1, h1, fc1_b, nullptr, 4096, 4096, 1024);
    gemm_bt<64, true, false, true, false><<<dim3(1024 / 64, 4096 / 128), 256, 0, stream>>>(
        h1, tfc2, out, fc2_b, x1, 4096, 1024, 4096);
}

// Round 3
// 408.675 us; speedup vs baseline: 1.2315x; 1.0961x over previous
//
#include <hip/hip_runtime.h>

// ---------------------------------------------------------------------------
// Transformer block for MI355X (gfx950).  R3: attention re-scheduled —
//   paired Q-tiles (qt=j & qt=31-j) per (b,h): 512 blocks x exactly 33
//   kt-iterations (perfect balance, no tail), double-buffered K/V staging
//   with ONE barrier per iteration (load latency hidden behind compute).
//   DPP softmax + XOR-swizzled LDS kept from R2 (bank conflicts = 0).
// ---------------------------------------------------------------------------

typedef short  bf16x8 __attribute__((ext_vector_type(8)));
typedef short  bf16x4 __attribute__((ext_vector_type(4)));
typedef float  fx4    __attribute__((ext_vector_type(4)));

#define DEV static __device__ __forceinline__

DEV short f2bf(float f) {                 // round-to-nearest-even fp32 -> bf16
    unsigned u = __builtin_bit_cast(unsigned, f);
    u += 0x7fffu + ((u >> 16) & 1u);
    return (short)(u >> 16);
}

// 16-lane (DPP "row") rotate-reduce on the VALU pipe. row_ror:N = 0x120|N.
template <int CTRL> DEV float dppmax(float v) {
    int x = __builtin_amdgcn_update_dpp(0, __builtin_bit_cast(int, v), CTRL, 0xF, 0xF, true);
    return fmaxf(v, __builtin_bit_cast(float, x));
}
template <int CTRL> DEV float dppadd(float v) {
    int x = __builtin_amdgcn_update_dpp(0, __builtin_bit_cast(int, v), CTRL, 0xF, 0xF, true);
    return v + __builtin_bit_cast(float, x);
}
DEV float rowmax16(float v) {
    v = dppmax<0x121>(v); v = dppmax<0x122>(v); v = dppmax<0x124>(v); v = dppmax<0x128>(v);
    return v;
}
DEV float rowsum16(float v) {
    v = dppadd<0x121>(v); v = dppadd<0x122>(v); v = dppadd<0x124>(v); v = dppadd<0x128>(v);
    return v;
}

// address-space casts for global_load_lds
#define AS1(p) ((__attribute__((address_space(1))) void*)(p))
#define AS3(p) ((__attribute__((address_space(3))) void*)(p))

// ---------------------------------------------------------------------------
// LayerNorm: fp32 [4096][1024] -> bf16 [4096][1024].  One block (256t) / row.
// ---------------------------------------------------------------------------
__global__ __launch_bounds__(256) void ln_kernel(const float* __restrict__ x,
                                                 const float* __restrict__ w,
                                                 const float* __restrict__ b,
                                                 short* __restrict__ out)
{
    int row = blockIdx.x;
    int tid = threadIdx.x;
    const float4 v = *(const float4*)(x + (size_t)row * 1024 + tid * 4);
    float s = v.x + v.y + v.z + v.w;
    float q = v.x * v.x + v.y * v.y + v.z * v.z + v.w * v.w;
#pragma unroll
    for (int off = 32; off > 0; off >>= 1) {
        s += __shfl_down(s, off);
        q += __shfl_down(q, off);
    }
    __shared__ float ls[4], lq[4];
    if ((tid & 63) == 0) { ls[tid >> 6] = s; lq[tid >> 6] = q; }
    __syncthreads();
    float S  = ls[0] + ls[1] + ls[2] + ls[3];
    float Q  = lq[0] + lq[1] + lq[2] + lq[3];
    float mu  = S * (1.0f / 1024.0f);
    float var = Q * (1.0f / 1024.0f) - mu * mu;
    float inv = rsqrtf(var + 1e-5f);
    float4 wv = *(const float4*)(w + tid * 4);
    float4 bv = *(const float4*)(b + tid * 4);
    bf16x4 o;
    o[0] = f2bf((v.x - mu) * inv * wv.x + bv.x);
    o[1] = f2bf((v.y - mu) * inv * wv.y + bv.y);
    o[2] = f2bf((v.z - mu) * inv * wv.z + bv.z);
    o[3] = f2bf((v.w - mu) * inv * wv.w + bv.w);
    *(bf16x4*)(out + (size_t)row * 1024 + tid * 4) = o;
}

// ---------------------------------------------------------------------------
// Weight transpose+cast: fp32 [R][C] -> bf16 [C][R].  32x32 tiles, block 32x8.
// ---------------------------------------------------------------------------
__global__ void transpose_f32_bf16(const float* __restrict__ in,
                                   short* __restrict__ out, int R, int C)
{
    __shared__ float tile[32][33];
    int c0 = blockIdx.x * 32, r0 = blockIdx.y * 32;
    int tx = threadIdx.x, ty = threadIdx.y;
#pragma unroll
    for (int dy = 0; dy < 32; dy += 8)
        tile[ty + dy][tx] = in[(size_t)(r0 + ty + dy) * C + c0 + tx];
    __syncthreads();
#pragma unroll
    for (int dy = 0; dy < 32; dy += 8)
        out[(size_t)(c0 + ty + dy) * R + r0 + tx] = f2bf(tile[tx][ty + dy]);
}

// ---------------------------------------------------------------------------
// Extract V^T per (b,h): qkv bf16 [4096][3072] cols[2048+h*64 .. +64)
//   -> vt [b][h][64][2048] (d-major, t contiguous) for PV's B-operand.
// ---------------------------------------------------------------------------
__global__ void vt_extract(const short* __restrict__ qkv, short* __restrict__ vt)
{
    __shared__ short tile[32][33];
    int t0 = blockIdx.x * 32, d0 = blockIdx.y * 32;
    int bh = blockIdx.z;                       // b*16 + h
    int tx = threadIdx.x, ty = threadIdx.y;
    size_t inbase  = (size_t)(bh >> 4) * 2048 * 3072 + 2048 + (bh & 15) * 64;
    size_t outbase = (size_t)bh * 64 * 2048;
#pragma unroll
    for (int dy = 0; dy < 32; dy += 8)
        tile[ty + dy][tx] = qkv[inbase + (size_t)(t0 + ty + dy) * 3072 + d0 + tx];
    __syncthreads();
#pragma unroll
    for (int dy = 0; dy < 32; dy += 8)
        vt[outbase + (size_t)(d0 + ty + dy) * 2048 + t0 + tx] = tile[tx][ty + dy];
}

// ---------------------------------------------------------------------------
// GEMM  C[M][N] = epi( A[M][K](bf16) * Bt[N][K](bf16)^T )
// 128xBN tile / 256 threads, BK=32, global_load_lds(16B) staging (m97 shape).
// BN=128 for wide outputs; BN=64 doubles block count for N=1024 outputs.
// Epilogue fusions: +bias[N], exact GELU, +resid(fp32)[M][N], out fp32|bf16.
// ---------------------------------------------------------------------------
template <int BN, bool BIAS, bool GELU, bool RESID, bool OUT_BF16>
__global__ __launch_bounds__(256) void gemm_bt(const short* __restrict__ A,
                                               const short* __restrict__ Bt,
                                               void* __restrict__ Cout,
                                               const float* __restrict__ bias,
                                               const float* __restrict__ resid,
                                               int M, int N, int K)
{
    constexpr int NJ = BN / 32;                    // 16-col tiles per wave
    __shared__ short As[128 * 32];
    __shared__ short Bs[BN * 32];
    int tid  = threadIdx.x;
    int lane = tid & 63, wv = tid >> 6;
    int quad = lane >> 4, l15 = lane & 15;
    int m0 = blockIdx.y * 128, n0 = blockIdx.x * BN;
    int wr = (wv >> 1) * 64, wc = (wv & 1) * (BN / 2);
    fx4 acc[4][NJ] = {};
    int srow = lane >> 2;                          // staging: 16 rows / chunk
    int scol = (lane & 3) * 8;
    const short* Ab = A  + (size_t)m0 * K;
    const short* Bb = Bt + (size_t)n0 * K;

    for (int k0 = 0; k0 < K; k0 += 32) {
#pragma unroll
        for (int c = wv; c < 8; c += 4) {
            int row = c * 16 + srow;
            __builtin_amdgcn_global_load_lds(AS1(Ab + (size_t)row * K + k0 + scol),
                                             AS3(&As[c * 512]), 16, 0, 0);
        }
#pragma unroll
        for (int c = wv; c < BN / 16; c += 4) {
            int row = c * 16 + srow;
            __builtin_amdgcn_global_load_lds(AS1(Bb + (size_t)row * K + k0 + scol),
                                             AS3(&Bs[c * 512]), 16, 0, 0);
        }
        __syncthreads();
        bf16x8 af[4], bfr[NJ];
#pragma unroll
        for (int i = 0; i < 4; ++i)
            af[i] = *(const bf16x8*)&As[(wr + i * 16 + l15) * 32 + quad * 8];
#pragma unroll
        for (int j = 0; j < NJ; ++j)
            bfr[j] = *(const bf16x8*)&Bs[(wc + j * 16 + l15) * 32 + quad * 8];
#pragma unroll
        for (int i = 0; i < 4; ++i)
#pragma unroll
            for (int j = 0; j < NJ; ++j)
                acc[i][j] = __builtin_amdgcn_mfma_f32_16x16x32_bf16(af[i], bfr[j], acc[i][j], 0, 0, 0);
        __syncthreads();
    }

#pragma unroll
    for (int i = 0; i < 4; ++i) {
#pragma unroll
        for (int j = 0; j < NJ; ++j) {
#pragma unroll
            for (int r = 0; r < 4; ++r) {
                int row = m0 + wr + i * 16 + quad * 4 + r;
                int col = n0 + wc + j * 16 + l15;
                float v = acc[i][j][r];
                if constexpr (BIAS)  v += bias[col];
                if constexpr (GELU)  v = 0.5f * v * (1.0f + erff(v * 0.70710678118654752f));
                if constexpr (RESID) v += resid[(size_t)row * N + col];
                if constexpr (OUT_BF16) ((short*)Cout)[(size_t)row * N + col] = f2bf(v);
                else                    ((float*)Cout)[(size_t)row * N + col] = v;
            }
        }
    }
}

// ---------------------------------------------------------------------------
// Flash attention (causal).  R3 structure:
//   Grid (16,16,2) = 512 blocks; block j handles Q-tiles qt=31-j then qt=j
//   for its (b,h) — exactly 33 kt-iterations per block (perfect balance).
//   K/V tiles (64x64) double-buffered: stage tile kt+1 into the alternate
//   buffer, compute tile kt, ONE __syncthreads per iteration (its vmcnt
//   drain lands ~1.5k cycles after load issue -> latency hidden).
//   XOR-swizzled LDS (conflict-free b128), DPP row_ror softmax (VALU pipe),
//   wave-private Ps (no barrier for the C->A layout roundtrip).
// ---------------------------------------------------------------------------
__global__ __launch_bounds__(256) void attn_kernel(const short* __restrict__ qkv,
                                                   const short* __restrict__ vt,
                                                   short* __restrict__ out)
{
    __shared__ short Ks[2][64 * 64];
    __shared__ short Vs[2][64 * 64];
    __shared__ short Ps[4 * 16 * 64];
    const float CS = 0.125f * 1.44269504088896f;  // 1/sqrt(64) * log2(e)
    int tid  = threadIdx.x, lane = tid & 63, wv = tid >> 6;
    int quad = lane >> 4, l15 = lane & 15;
    int b = blockIdx.z, h = blockIdx.y, j = blockIdx.x;

    const size_t kbase = (size_t)b * 2048 * 3072 + 1024 + h * 64;
    const size_t vbase = (size_t)(b * 16 + h) * 64 * 2048;
    int srow = lane >> 3;                 // 0..7 : row within 8-row chunk
    int sg   = lane & 7;                  // LDS granule slot
    int scol = (sg ^ srow) * 8;           // global col granule for this slot
    int rg0  = (quad ^ (l15 & 7)) * 8;    // swizzled read offset (granule=quad)

    for (int item = 0; item < 2; ++item) {
        int qt = item ? j : 31 - j;       // big tile first
        int q0 = qt * 64;

        bf16x8 qf[2];
#pragma unroll
        for (int ks = 0; ks < 2; ++ks)
            qf[ks] = *(const bf16x8*)&qkv[(size_t)(b * 2048 + q0 + wv * 16 + l15) * 3072
                                           + h * 64 + ks * 32 + quad * 8];
        float mi[4], li[4];
        fx4 oacc[4] = {};
#pragma unroll
        for (int r = 0; r < 4; ++r) { mi[r] = -1e30f; li[r] = 0.0f; }

        // prologue: stage tile 0 into buffer 0
#pragma unroll
        for (int c = wv; c < 8; c += 4) {
            int row = c * 8 + srow;
            __builtin_amdgcn_global_load_lds(AS1(qkv + kbase + (size_t)row * 3072 + scol),
                                             AS3(&Ks[0][c * 512]), 16, 0, 0);
            __builtin_amdgcn_global_load_lds(AS1(vt + vbase + (size_t)row * 2048 + scol),
                                             AS3(&Vs[0][c * 512]), 16, 0, 0);
        }
        __syncthreads();

        for (int kt = 0; kt <= qt; ++kt) {
            int cur = kt & 1;
            if (kt < qt) {                 // stage next tile into alt buffer
                int nb = cur ^ 1;
                int tn = (kt + 1) * 64;
#pragma unroll
                for (int c = wv; c < 8; c += 4) {
                    int row = c * 8 + srow;
                    __builtin_amdgcn_global_load_lds(AS1(qkv + kbase + (size_t)(tn + row) * 3072 + scol),
                                                     AS3(&Ks[nb][c * 512]), 16, 0, 0);
                    __builtin_amdgcn_global_load_lds(AS1(vt + vbase + (size_t)row * 2048 + tn + scol),
                                                     AS3(&Vs[nb][c * 512]), 16, 0, 0);
                }
            }

            fx4 s[4];
#pragma unroll
            for (int nt = 0; nt < 4; ++nt) {
                bf16x8 kf0 = *(const bf16x8*)&Ks[cur][(nt * 16 + l15) * 64 + rg0];
                bf16x8 kf1 = *(const bf16x8*)&Ks[cur][(nt * 16 + l15) * 64 + (rg0 ^ 32)];
                fx4 z = {0.f, 0.f, 0.f, 0.f};
                z = __builtin_amdgcn_mfma_f32_16x16x32_bf16(qf[0], kf0, z, 0, 0, 0);
                z = __builtin_amdgcn_mfma_f32_16x16x32_bf16(qf[1], kf1, z, 0, 0, 0);
                s[nt] = z;
            }
            if (kt == qt) {                // diagonal tile: causal mask
#pragma unroll
                for (int nt = 0; nt < 4; ++nt)
#pragma unroll
                    for (int r = 0; r < 4; ++r)
                        if (nt * 16 + l15 > wv * 16 + quad * 4 + r) s[nt][r] = -1e30f;
            }

            float mnew[4], alpha[4], rsum[4];
#pragma unroll
            for (int r = 0; r < 4; ++r) {
                float v = fmaxf(fmaxf(s[0][r], s[1][r]), fmaxf(s[2][r], s[3][r]));
                v = rowmax16(v);
                mnew[r]  = fmaxf(mi[r], v);
                alpha[r] = exp2f((mi[r] - mnew[r]) * CS);
                mi[r] = mnew[r];
                rsum[r] = 0.0f;
            }
#pragma unroll
            for (int nt = 0; nt < 4; ++nt)
#pragma unroll
                for (int r = 0; r < 4; ++r) {
                    float p = exp2f((s[nt][r] - mnew[r]) * CS);
                    rsum[r] += p;
                    int rr = quad * 4 + r;
                    int col = nt * 16 + l15;
                    int g = (col >> 3) ^ (rr & 7);
                    Ps[wv * 1024 + rr * 64 + g * 8 + (col & 7)] = f2bf(p);
                }
#pragma unroll
            for (int r = 0; r < 4; ++r) {
                float v = rowsum16(rsum[r]);
                li[r] = li[r] * alpha[r] + v;
#pragma unroll
                for (int dt = 0; dt < 4; ++dt) oacc[dt][r] *= alpha[r];
            }

            // Ps is wave-private; DS ops from one wave execute in order.
            bf16x8 pf0 = *(const bf16x8*)&Ps[wv * 1024 + l15 * 64 + rg0];
            bf16x8 pf1 = *(const bf16x8*)&Ps[wv * 1024 + l15 * 64 + (rg0 ^ 32)];
#pragma unroll
            for (int dt = 0; dt < 4; ++dt) {
                bf16x8 vf0 = *(const bf16x8*)&Vs[cur][(dt * 16 + l15) * 64 + rg0];
                bf16x8 vf1 = *(const bf16x8*)&Vs[cur][(dt * 16 + l15) * 64 + (rg0 ^ 32)];
                oacc[dt] = __builtin_amdgcn_mfma_f32_16x16x32_bf16(pf0, vf0, oacc[dt], 0, 0, 0);
                oacc[dt] = __builtin_amdgcn_mfma_f32_16x16x32_bf16(pf1, vf1, oacc[dt], 0, 0, 0);
            }
            // ONE barrier: syncs compute on buf[cur] AND drains next-tile loads
            __syncthreads();
        }

        float inv[4];
#pragma unroll
        for (int r = 0; r < 4; ++r) inv[r] = 1.0f / li[r];
#pragma unroll
        for (int dt = 0; dt < 4; ++dt)
#pragma unroll
            for (int r = 0; r < 4; ++r) {
                int row = q0 + wv * 16 + quad * 4 + r;
                int col = h * 64 + dt * 16 + l15;
                out[((size_t)b * 2048 + row) * 1024 + col] = f2bf(oacc[dt][r] * inv[r]);
            }
    }
}

// ---------------------------------------------------------------------------
extern "C" void kernel_launch(void* const* d_in, const int* in_sizes, int n_in,
                              void* d_out, int out_size, void* d_ws, size_t ws_size,
                              hipStream_t stream)
{
    const float* x      = (const float*)d_in[0];
    const float* w_qkv  = (const float*)d_in[1];
    const float* w_proj = (const float*)d_in[2];
    const float* ln1_w  = (const float*)d_in[3];
    const float* ln1_b  = (const float*)d_in[4];
    const float* ln2_w  = (const float*)d_in[5];
    const float* ln2_b  = (const float*)d_in[6];
    const float* fc1_w  = (const float*)d_in[7];
    const float* fc1_b  = (const float*)d_in[8];
    const float* fc2_w  = (const float*)d_in[9];
    const float* fc2_b  = (const float*)d_in[10];
    float* out = (float*)d_out;
    char*  ws  = (char*)d_ws;

    size_t off = 0;
    auto alloc = [&](size_t bytes) { void* p = ws + off; off += (bytes + 255) & ~(size_t)255; return p; };
    short* tw_qkv  = (short*)alloc((size_t)3072 * 1024 * 2);
    short* tw_proj = (short*)alloc((size_t)1024 * 1024 * 2);
    short* tfc1    = (short*)alloc((size_t)4096 * 1024 * 2);
    short* tfc2    = (short*)alloc((size_t)1024 * 4096 * 2);
    short* xn      = (short*)alloc((size_t)4096 * 1024 * 2);
    short* qkvb    = (short*)alloc((size_t)4096 * 3072 * 2);
    short* vtb     = (short*)alloc((size_t)32 * 64 * 2048 * 2);
    short* attnb   = (short*)alloc((size_t)4096 * 1024 * 2);
    float* x1      = (float*)alloc((size_t)4096 * 1024 * 4);
    short* h1      = qkvb;  // alias: qkv+vt dead after attention; h1 = 33.55MB

    dim3 tb(32, 8);
    transpose_f32_bf16<<<dim3(3072 / 32, 1024 / 32), tb, 0, stream>>>(w_qkv, tw_qkv, 1024, 3072);
    transpose_f32_bf16<<<dim3(1024 / 32, 1024 / 32), tb, 0, stream>>>(w_proj, tw_proj, 1024, 1024);
    transpose_f32_bf16<<<dim3(4096 / 32, 1024 / 32), tb, 0, stream>>>(fc1_w, tfc1, 1024, 4096);
    transpose_f32_bf16<<<dim3(1024 / 32, 4096 / 32), tb, 0, stream>>>(fc2_w, tfc2, 4096, 1024);

    ln_kernel<<<4096, 256, 0, stream>>>(x, ln1_w, ln1_b, xn);
    gemm_bt<128, false, false, false, true><<<dim3(3072 / 128, 4096 / 128), 256, 0, stream>>>(
        xn, tw_qkv, qkvb, nullptr, nullptr, 4096, 3072, 1024);
    vt_extract<<<dim3(2048 / 32, 64 / 32, 32), tb, 0, stream>>>(qkvb, vtb);
    attn_kernel<<<dim3(16, 16, 2), 256, 0, stream>>>(qkvb, vtb, attnb);
    gemm_bt<64, false, false, true, false><<<dim3(1024 / 64, 4096 / 128), 256, 0, stream>>>(
        attnb, tw_proj, x1, nullptr, x, 4096, 1024, 1024);
    ln_kernel<<<4096, 256, 0, stream>>>(x1, ln2_w, ln2_b, xn);
    gemm_bt<128, true, true, false, true><<<dim3(4096 / 128, 4096 / 128), 256, 0, stream>>>(
        xn, tfc1, h1, fc1_b, nullptr, 4096, 4096, 1024);
    gemm_bt<64, true, false, true, false><<<dim3(1024 / 64, 4096 / 128), 256, 0, stream>>>(
        h1, tfc2, out, fc2_b, x1, 4096, 1024, 4096);
}

// Round 4
// 397.493 us; speedup vs baseline: 1.2661x; 1.0281x over previous
//
#include <hip/hip_runtime.h>

// ---------------------------------------------------------------------------
// Transformer block for MI355X (gfx950).  R4: GEMM K-loop restructured —
//   double-buffered LDS + ONE barrier per k-iter (R3 attention pattern),
//   4-granule XOR-swizzled LDS tiles (8-way -> 4-way ds_read_b128 conflicts),
//   split-K x2 for fc2/proj (4 blocks/CU instead of 2) with fp32 partials
//   (slot0 in-place in the destination, slot1 in ws) + reduce2 epilogue.
// ---------------------------------------------------------------------------

typedef short  bf16x8 __attribute__((ext_vector_type(8)));
typedef short  bf16x4 __attribute__((ext_vector_type(4)));
typedef float  fx4    __attribute__((ext_vector_type(4)));

#define DEV static __device__ __forceinline__

DEV short f2bf(float f) {                 // round-to-nearest-even fp32 -> bf16
    unsigned u = __builtin_bit_cast(unsigned, f);
    u += 0x7fffu + ((u >> 16) & 1u);
    return (short)(u >> 16);
}

// 16-lane (DPP "row") rotate-reduce on the VALU pipe. row_ror:N = 0x120|N.
template <int CTRL> DEV float dppmax(float v) {
    int x = __builtin_amdgcn_update_dpp(0, __builtin_bit_cast(int, v), CTRL, 0xF, 0xF, true);
    return fmaxf(v, __builtin_bit_cast(float, x));
}
template <int CTRL> DEV float dppadd(float v) {
    int x = __builtin_amdgcn_update_dpp(0, __builtin_bit_cast(int, v), CTRL, 0xF, 0xF, true);
    return v + __builtin_bit_cast(float, x);
}
DEV float rowmax16(float v) {
    v = dppmax<0x121>(v); v = dppmax<0x122>(v); v = dppmax<0x124>(v); v = dppmax<0x128>(v);
    return v;
}
DEV float rowsum16(float v) {
    v = dppadd<0x121>(v); v = dppadd<0x122>(v); v = dppadd<0x124>(v); v = dppadd<0x128>(v);
    return v;
}

// address-space casts for global_load_lds
#define AS1(p) ((__attribute__((address_space(1))) void*)(p))
#define AS3(p) ((__attribute__((address_space(3))) void*)(p))

// ---------------------------------------------------------------------------
// LayerNorm: fp32 [4096][1024] -> bf16 [4096][1024].  One block (256t) / row.
// ---------------------------------------------------------------------------
__global__ __launch_bounds__(256) void ln_kernel(const float* __restrict__ x,
                                                 const float* __restrict__ w,
                                                 const float* __restrict__ b,
                                                 short* __restrict__ out)
{
    int row = blockIdx.x;
    int tid = threadIdx.x;
    const float4 v = *(const float4*)(x + (size_t)row * 1024 + tid * 4);
    float s = v.x + v.y + v.z + v.w;
    float q = v.x * v.x + v.y * v.y + v.z * v.z + v.w * v.w;
#pragma unroll
    for (int off = 32; off > 0; off >>= 1) {
        s += __shfl_down(s, off);
        q += __shfl_down(q, off);
    }
    __shared__ float ls[4], lq[4];
    if ((tid & 63) == 0) { ls[tid >> 6] = s; lq[tid >> 6] = q; }
    __syncthreads();
    float S  = ls[0] + ls[1] + ls[2] + ls[3];
    float Q  = lq[0] + lq[1] + lq[2] + lq[3];
    float mu  = S * (1.0f / 1024.0f);
    float var = Q * (1.0f / 1024.0f) - mu * mu;
    float inv = rsqrtf(var + 1e-5f);
    float4 wv = *(const float4*)(w + tid * 4);
    float4 bv = *(const float4*)(b + tid * 4);
    bf16x4 o;
    o[0] = f2bf((v.x - mu) * inv * wv.x + bv.x);
    o[1] = f2bf((v.y - mu) * inv * wv.y + bv.y);
    o[2] = f2bf((v.z - mu) * inv * wv.z + bv.z);
    o[3] = f2bf((v.w - mu) * inv * wv.w + bv.w);
    *(bf16x4*)(out + (size_t)row * 1024 + tid * 4) = o;
}

// ---------------------------------------------------------------------------
// Weight transpose+cast: fp32 [R][C] -> bf16 [C][R].  32x32 tiles, block 32x8.
// ---------------------------------------------------------------------------
__global__ void transpose_f32_bf16(const float* __restrict__ in,
                                   short* __restrict__ out, int R, int C)
{
    __shared__ float tile[32][33];
    int c0 = blockIdx.x * 32, r0 = blockIdx.y * 32;
    int tx = threadIdx.x, ty = threadIdx.y;
#pragma unroll
    for (int dy = 0; dy < 32; dy += 8)
        tile[ty + dy][tx] = in[(size_t)(r0 + ty + dy) * C + c0 + tx];
    __syncthreads();
#pragma unroll
    for (int dy = 0; dy < 32; dy += 8)
        out[(size_t)(c0 + ty + dy) * R + r0 + tx] = f2bf(tile[tx][ty + dy]);
}

// ---------------------------------------------------------------------------
// Extract V^T per (b,h): qkv bf16 [4096][3072] cols[2048+h*64 .. +64)
//   -> vt [b][h][64][2048] (d-major, t contiguous) for PV's B-operand.
// ---------------------------------------------------------------------------
__global__ void vt_extract(const short* __restrict__ qkv, short* __restrict__ vt)
{
    __shared__ short tile[32][33];
    int t0 = blockIdx.x * 32, d0 = blockIdx.y * 32;
    int bh = blockIdx.z;                       // b*16 + h
    int tx = threadIdx.x, ty = threadIdx.y;
    size_t inbase  = (size_t)(bh >> 4) * 2048 * 3072 + 2048 + (bh & 15) * 64;
    size_t outbase = (size_t)bh * 64 * 2048;
#pragma unroll
    for (int dy = 0; dy < 32; dy += 8)
        tile[ty + dy][tx] = qkv[inbase + (size_t)(t0 + ty + dy) * 3072 + d0 + tx];
    __syncthreads();
#pragma unroll
    for (int dy = 0; dy < 32; dy += 8)
        vt[outbase + (size_t)(d0 + ty + dy) * 2048 + t0 + tx] = tile[tx][ty + dy];
}

// ---------------------------------------------------------------------------
// GEMM  C[M][N] = epi( A[M][K](bf16) * Bt[N][K](bf16)^T )
// 128xBN tile / 256 threads, BK=32, global_load_lds(16B), double-buffered
// LDS with ONE barrier per k-iter.  4-granule XOR swizzle kills most
// ds_read_b128 bank conflicts.  Split-K: SK = gridDim.z; PARTIAL mode writes
// fp32 partial sums (slot ks=0 -> Cout, ks=1 -> Cout2), no epilogue.
// Epilogue fusions (non-partial): +bias[N], exact GELU, +resid, fp32|bf16 out.
// ---------------------------------------------------------------------------
template <int BN, bool BIAS, bool GELU, bool RESID, bool OUT_BF16, bool PARTIAL>
__global__ __launch_bounds__(256) void gemm_bt(const short* __restrict__ A,
                                               const short* __restrict__ Bt,
                                               void* __restrict__ Cout,
                                               void* __restrict__ Cout2,
                                               const float* __restrict__ bias,
                                               const float* __restrict__ resid,
                                               int M, int N, int K)
{
    constexpr int NJ = BN / 32;                    // 16-col tiles per wave
    __shared__ short As[2][128 * 32];
    __shared__ short Bs[2][BN * 32];
    int tid  = threadIdx.x;
    int lane = tid & 63, wv = tid >> 6;
    int quad = lane >> 4, l15 = lane & 15;
    int m0 = blockIdx.y * 128, n0 = blockIdx.x * BN;
    int SK   = gridDim.z;
    int kbeg = blockIdx.z * (K / SK);
    int NK   = (K / SK) / 32;
    int wr = (wv >> 1) * 64, wc = (wv & 1) * (BN / 2);
    fx4 acc[4][NJ] = {};
    int srow = lane >> 2;                          // staging: 16 rows / chunk
    int scol = ((lane & 3) ^ (srow & 3)) * 8;      // XOR-swizzled src granule
    int rg   = (quad ^ (l15 & 3)) * 8;             // swizzled fragment offset
    const short* Ab = A  + (size_t)m0 * K;
    const short* Bb = Bt + (size_t)n0 * K;

    auto stage = [&](int buf, int k0) {
#pragma unroll
        for (int c = wv; c < 8; c += 4) {
            int row = c * 16 + srow;
            __builtin_amdgcn_global_load_lds(AS1(Ab + (size_t)row * K + k0 + scol),
                                             AS3(&As[buf][c * 512]), 16, 0, 0);
        }
#pragma unroll
        for (int c = wv; c < BN / 16; c += 4) {
            int row = c * 16 + srow;
            __builtin_amdgcn_global_load_lds(AS1(Bb + (size_t)row * K + k0 + scol),
                                             AS3(&Bs[buf][c * 512]), 16, 0, 0);
        }
    };

    stage(0, kbeg);
    __syncthreads();
    for (int kt = 0; kt < NK; ++kt) {
        int cur = kt & 1;
        if (kt + 1 < NK) stage(cur ^ 1, kbeg + (kt + 1) * 32);
        bf16x8 af[4], bfr[NJ];
#pragma unroll
        for (int i = 0; i < 4; ++i)
            af[i] = *(const bf16x8*)&As[cur][(wr + i * 16 + l15) * 32 + rg];
#pragma unroll
        for (int j = 0; j < NJ; ++j)
            bfr[j] = *(const bf16x8*)&Bs[cur][(wc + j * 16 + l15) * 32 + rg];
#pragma unroll
        for (int i = 0; i < 4; ++i)
#pragma unroll
            for (int j = 0; j < NJ; ++j)
                acc[i][j] = __builtin_amdgcn_mfma_f32_16x16x32_bf16(af[i], bfr[j], acc[i][j], 0, 0, 0);
        // ONE barrier: completes LDS reads of buf[cur] (so next stage may
        // overwrite buf[cur^1]... which was read last iter) AND drains this
        // iteration's global_load_lds into buf[cur^1].
        __syncthreads();
    }

    if constexpr (PARTIAL) {
        float* P = blockIdx.z ? (float*)Cout2 : (float*)Cout;
#pragma unroll
        for (int i = 0; i < 4; ++i)
#pragma unroll
            for (int j = 0; j < NJ; ++j)
#pragma unroll
                for (int r = 0; r < 4; ++r) {
                    int row = m0 + wr + i * 16 + quad * 4 + r;
                    int col = n0 + wc + j * 16 + l15;
                    P[(size_t)row * N + col] = acc[i][j][r];
                }
    } else {
#pragma unroll
        for (int i = 0; i < 4; ++i)
#pragma unroll
            for (int j = 0; j < NJ; ++j)
#pragma unroll
                for (int r = 0; r < 4; ++r) {
                    int row = m0 + wr + i * 16 + quad * 4 + r;
                    int col = n0 + wc + j * 16 + l15;
                    float v = acc[i][j][r];
                    if constexpr (BIAS)  v += bias[col];
                    if constexpr (GELU)  v = 0.5f * v * (1.0f + erff(v * 0.70710678118654752f));
                    if constexpr (RESID) v += resid[(size_t)row * N + col];
                    if constexpr (OUT_BF16) ((short*)Cout)[(size_t)row * N + col] = f2bf(v);
                    else                    ((float*)Cout)[(size_t)row * N + col] = v;
                }
    }
}

// ---------------------------------------------------------------------------
// Split-K reduce: out = p0 + p1 + resid (+ bias).  float4 vectorized.
// Safe in-place when out == p0 (each thread reads then writes its own slot).
// ---------------------------------------------------------------------------
template <bool BIAS>
__global__ __launch_bounds__(256) void reduce2(const float* __restrict__ p0,
                                               const float* __restrict__ p1,
                                               const float* __restrict__ resid,
                                               const float* __restrict__ bias,
                                               float* __restrict__ out, int N)
{
    size_t idx = ((size_t)blockIdx.x * 256 + threadIdx.x) * 4;
    float4 a = *(const float4*)(p0 + idx);
    float4 b = *(const float4*)(p1 + idx);
    float4 r = *(const float4*)(resid + idx);
    float4 v;
    v.x = a.x + b.x + r.x; v.y = a.y + b.y + r.y;
    v.z = a.z + b.z + r.z; v.w = a.w + b.w + r.w;
    if constexpr (BIAS) {
        const float4 bv = *(const float4*)(bias + (idx & (N - 1)));
        v.x += bv.x; v.y += bv.y; v.z += bv.z; v.w += bv.w;
    }
    *(float4*)(out + idx) = v;
}

// ---------------------------------------------------------------------------
// Flash attention (causal).  R3 structure (unchanged):
//   paired Q-tiles (qt=31-j then qt=j): 512 blocks x exactly 33 kt-iters,
//   double-buffered K/V staging, ONE barrier/iter, XOR-swizzled LDS
//   (0 bank conflicts), DPP row_ror softmax, wave-private Ps roundtrip.
// ---------------------------------------------------------------------------
__global__ __launch_bounds__(256) void attn_kernel(const short* __restrict__ qkv,
                                                   const short* __restrict__ vt,
                                                   short* __restrict__ out)
{
    __shared__ short Ks[2][64 * 64];
    __shared__ short Vs[2][64 * 64];
    __shared__ short Ps[4 * 16 * 64];
    const float CS = 0.125f * 1.44269504088896f;  // 1/sqrt(64) * log2(e)
    int tid  = threadIdx.x, lane = tid & 63, wv = tid >> 6;
    int quad = lane >> 4, l15 = lane & 15;
    int b = blockIdx.z, h = blockIdx.y, j = blockIdx.x;

    const size_t kbase = (size_t)b * 2048 * 3072 + 1024 + h * 64;
    const size_t vbase = (size_t)(b * 16 + h) * 64 * 2048;
    int srow = lane >> 3;                 // 0..7 : row within 8-row chunk
    int sg   = lane & 7;                  // LDS granule slot
    int scol = (sg ^ srow) * 8;           // global col granule for this slot
    int rg0  = (quad ^ (l15 & 7)) * 8;    // swizzled read offset (granule=quad)

    for (int item = 0; item < 2; ++item) {
        int qt = item ? j : 31 - j;       // big tile first
        int q0 = qt * 64;

        bf16x8 qf[2];
#pragma unroll
        for (int ks = 0; ks < 2; ++ks)
            qf[ks] = *(const bf16x8*)&qkv[(size_t)(b * 2048 + q0 + wv * 16 + l15) * 3072
                                           + h * 64 + ks * 32 + quad * 8];
        float mi[4], li[4];
        fx4 oacc[4] = {};
#pragma unroll
        for (int r = 0; r < 4; ++r) { mi[r] = -1e30f; li[r] = 0.0f; }

        // prologue: stage tile 0 into buffer 0
#pragma unroll
        for (int c = wv; c < 8; c += 4) {
            int row = c * 8 + srow;
            __builtin_amdgcn_global_load_lds(AS1(qkv + kbase + (size_t)row * 3072 + scol),
                                             AS3(&Ks[0][c * 512]), 16, 0, 0);
            __builtin_amdgcn_global_load_lds(AS1(vt + vbase + (size_t)row * 2048 + scol),
                                             AS3(&Vs[0][c * 512]), 16, 0, 0);
        }
        __syncthreads();

        for (int kt = 0; kt <= qt; ++kt) {
            int cur = kt & 1;
            if (kt < qt) {                 // stage next tile into alt buffer
                int nb = cur ^ 1;
                int tn = (kt + 1) * 64;
#pragma unroll
                for (int c = wv; c < 8; c += 4) {
                    int row = c * 8 + srow;
                    __builtin_amdgcn_global_load_lds(AS1(qkv + kbase + (size_t)(tn + row) * 3072 + scol),
                                                     AS3(&Ks[nb][c * 512]), 16, 0, 0);
                    __builtin_amdgcn_global_load_lds(AS1(vt + vbase + (size_t)row * 2048 + tn + scol),
                                                     AS3(&Vs[nb][c * 512]), 16, 0, 0);
                }
            }

            fx4 s[4];
#pragma unroll
            for (int nt = 0; nt < 4; ++nt) {
                bf16x8 kf0 = *(const bf16x8*)&Ks[cur][(nt * 16 + l15) * 64 + rg0];
                bf16x8 kf1 = *(const bf16x8*)&Ks[cur][(nt * 16 + l15) * 64 + (rg0 ^ 32)];
                fx4 z = {0.f, 0.f, 0.f, 0.f};
                z = __builtin_amdgcn_mfma_f32_16x16x32_bf16(qf[0], kf0, z, 0, 0, 0);
                z = __builtin_amdgcn_mfma_f32_16x16x32_bf16(qf[1], kf1, z, 0, 0, 0);
                s[nt] = z;
            }
            if (kt == qt) {                // diagonal tile: causal mask
#pragma unroll
                for (int nt = 0; nt < 4; ++nt)
#pragma unroll
                    for (int r = 0; r < 4; ++r)
                        if (nt * 16 + l15 > wv * 16 + quad * 4 + r) s[nt][r] = -1e30f;
            }

            float mnew[4], alpha[4], rsum[4];
#pragma unroll
            for (int r = 0; r < 4; ++r) {
                float v = fmaxf(fmaxf(s[0][r], s[1][r]), fmaxf(s[2][r], s[3][r]));
                v = rowmax16(v);
                mnew[r]  = fmaxf(mi[r], v);
                alpha[r] = exp2f((mi[r] - mnew[r]) * CS);
                mi[r] = mnew[r];
                rsum[r] = 0.0f;
            }
#pragma unroll
            for (int nt = 0; nt < 4; ++nt)
#pragma unroll
                for (int r = 0; r < 4; ++r) {
                    float p = exp2f((s[nt][r] - mnew[r]) * CS);
                    rsum[r] += p;
                    int rr = quad * 4 + r;
                    int col = nt * 16 + l15;
                    int g = (col >> 3) ^ (rr & 7);
                    Ps[wv * 1024 + rr * 64 + g * 8 + (col & 7)] = f2bf(p);
                }
#pragma unroll
            for (int r = 0; r < 4; ++r) {
                float v = rowsum16(rsum[r]);
                li[r] = li[r] * alpha[r] + v;
#pragma unroll
                for (int dt = 0; dt < 4; ++dt) oacc[dt][r] *= alpha[r];
            }

            // Ps is wave-private; DS ops from one wave execute in order.
            bf16x8 pf0 = *(const bf16x8*)&Ps[wv * 1024 + l15 * 64 + rg0];
            bf16x8 pf1 = *(const bf16x8*)&Ps[wv * 1024 + l15 * 64 + (rg0 ^ 32)];
#pragma unroll
            for (int dt = 0; dt < 4; ++dt) {
                bf16x8 vf0 = *(const bf16x8*)&Vs[cur][(dt * 16 + l15) * 64 + rg0];
                bf16x8 vf1 = *(const bf16x8*)&Vs[cur][(dt * 16 + l15) * 64 + (rg0 ^ 32)];
                oacc[dt] = __builtin_amdgcn_mfma_f32_16x16x32_bf16(pf0, vf0, oacc[dt], 0, 0, 0);
                oacc[dt] = __builtin_amdgcn_mfma_f32_16x16x32_bf16(pf1, vf1, oacc[dt], 0, 0, 0);
            }
            __syncthreads();
        }

        float inv[4];
#pragma unroll
        for (int r = 0; r < 4; ++r) inv[r] = 1.0f / li[r];
#pragma unroll
        for (int dt = 0; dt < 4; ++dt)
#pragma unroll
            for (int r = 0; r < 4; ++r) {
                int row = q0 + wv * 16 + quad * 4 + r;
                int col = h * 64 + dt * 16 + l15;
                out[((size_t)b * 2048 + row) * 1024 + col] = f2bf(oacc[dt][r] * inv[r]);
            }
    }
}

// ---------------------------------------------------------------------------
extern "C" void kernel_launch(void* const* d_in, const int* in_sizes, int n_in,
                              void* d_out, int out_size, void* d_ws, size_t ws_size,
                              hipStream_t stream)
{
    const float* x      = (const float*)d_in[0];
    const float* w_qkv  = (const float*)d_in[1];
    const float* w_proj = (const float*)d_in[2];
    const float* ln1_w  = (const float*)d_in[3];
    const float* ln1_b  = (const float*)d_in[4];
    const float* ln2_w  = (const float*)d_in[5];
    const float* ln2_b  = (const float*)d_in[6];
    const float* fc1_w  = (const float*)d_in[7];
    const float* fc1_b  = (const float*)d_in[8];
    const float* fc2_w  = (const float*)d_in[9];
    const float* fc2_b  = (const float*)d_in[10];
    float* out = (float*)d_out;
    char*  ws  = (char*)d_ws;

    size_t off = 0;
    auto alloc = [&](size_t bytes) { void* p = ws + off; off += (bytes + 255) & ~(size_t)255; return p; };
    short* tw_qkv  = (short*)alloc((size_t)3072 * 1024 * 2);
    short* tw_proj = (short*)alloc((size_t)1024 * 1024 * 2);
    short* tfc1    = (short*)alloc((size_t)4096 * 1024 * 2);
    short* tfc2    = (short*)alloc((size_t)1024 * 4096 * 2);
    short* xn      = (short*)alloc((size_t)4096 * 1024 * 2);
    short* qkvb    = (short*)alloc((size_t)4096 * 3072 * 2);
    short* vtb     = (short*)alloc((size_t)32 * 64 * 2048 * 2);
    short* attnb   = (short*)alloc((size_t)4096 * 1024 * 2);
    float* x1      = (float*)alloc((size_t)4096 * 1024 * 4);
    float* pk      = (float*)alloc((size_t)4096 * 1024 * 4);  // split-K slot 1
    short* h1      = qkvb;  // alias: qkv+vt dead after attention; h1 = 33.55MB

    dim3 tb(32, 8);
    transpose_f32_bf16<<<dim3(3072 / 32, 1024 / 32), tb, 0, stream>>>(w_qkv, tw_qkv, 1024, 3072);
    transpose_f32_bf16<<<dim3(1024 / 32, 1024 / 32), tb, 0, stream>>>(w_proj, tw_proj, 1024, 1024);
    transpose_f32_bf16<<<dim3(4096 / 32, 1024 / 32), tb, 0, stream>>>(fc1_w, tfc1, 1024, 4096);
    transpose_f32_bf16<<<dim3(1024 / 32, 4096 / 32), tb, 0, stream>>>(fc2_w, tfc2, 4096, 1024);

    ln_kernel<<<4096, 256, 0, stream>>>(x, ln1_w, ln1_b, xn);
    // qkv: [4096,1024]x[1024,3072] -> bf16
    gemm_bt<128, false, false, false, true, false><<<dim3(24, 32, 1), 256, 0, stream>>>(
        xn, tw_qkv, qkvb, nullptr, nullptr, nullptr, 4096, 3072, 1024);
    vt_extract<<<dim3(2048 / 32, 64 / 32, 32), tb, 0, stream>>>(qkvb, vtb);
    attn_kernel<<<dim3(16, 16, 2), 256, 0, stream>>>(qkvb, vtb, attnb);
    // proj: split-K x2 partials (slot0 -> x1 in place, slot1 -> pk), then
    // reduce: x1 = p0 + p1 + x
    gemm_bt<64, false, false, false, false, true><<<dim3(16, 32, 2), 256, 0, stream>>>(
        attnb, tw_proj, x1, pk, nullptr, nullptr, 4096, 1024, 1024);
    reduce2<false><<<4096, 256, 0, stream>>>(x1, pk, x, nullptr, x1, 1024);
    ln_kernel<<<4096, 256, 0, stream>>>(x1, ln2_w, ln2_b, xn);
    // fc1: [4096,1024]x[1024,4096] + bias + GELU -> bf16
    gemm_bt<128, true, true, false, true, false><<<dim3(32, 32, 1), 256, 0, stream>>>(
        xn, tfc1, h1, nullptr, fc1_b, nullptr, 4096, 4096, 1024);
    // fc2: split-K x2 partials (slot0 -> out in place, slot1 -> pk), then
    // reduce: out = p0 + p1 + fc2_b + x1
    gemm_bt<64, false, false, false, false, true><<<dim3(16, 32, 2), 256, 0, stream>>>(
        h1, tfc2, out, pk, nullptr, nullptr, 4096, 1024, 4096);
    reduce2<true><<<4096, 256, 0, stream>>>(out, pk, x1, fc2_b, out, 1024);
}